// Round 1
// baseline (450.064 us; speedup 1.0000x reference)
//
#include <hip/hip_runtime.h>
#include <cstddef>

// Problem constants (from reference setup_inputs).
constexpr int N_  = 32;
constexpr int H_  = 16;
constexpr int E_  = 128;   // = D
constexpr int D_  = 128;
constexpr int S_  = 2047;
constexpr int SP1 = 2048;  // S+1
constexpr int NH  = N_ * H_;

constexpr int ROWS_PER_BLOCK = 256;
constexpr int CHUNKS = SP1 / ROWS_PER_BLOCK;  // 8

// ---------------------------------------------------------------------------
// k1: stream keys_cache + appended key -> keys_out, and compute
//     scores[n,h,s] = dot(query[n,h,:], keys[n,h,s,:]) in the same pass.
// Layout: 256 thr = 4 waves; each wave handles 2 rows/iter (32 lanes x float4
// = 128 floats per row). 32-lane shuffle reduce for the dot product.
// ---------------------------------------------------------------------------
__global__ __launch_bounds__(256) void k1_keys_scores(
    const float* __restrict__ query, const float* __restrict__ key,
    const float* __restrict__ keys_cache,
    float* __restrict__ keys_out, float* __restrict__ scores)
{
  const int bid   = blockIdx.x;
  const int nh    = bid / CHUNKS;
  const int chunk = bid % CHUNKS;
  const int tid   = threadIdx.x;
  const int wave  = tid >> 6;
  const int lane  = tid & 63;
  const int half  = lane >> 5;
  const int lcol  = lane & 31;

  const float4 q4 = *reinterpret_cast<const float4*>(query + (size_t)nh * E_ + lcol * 4);

  #pragma unroll 4
  for (int it = 0; it < ROWS_PER_BLOCK / 8; ++it) {
    const int r = it * 8 + wave * 2 + half;
    const int s = chunk * ROWS_PER_BLOCK + r;
    const float* src = (s < S_) ? (keys_cache + ((size_t)nh * S_ + s) * E_)
                                : (key + (size_t)nh * E_);
    float4 k4 = *reinterpret_cast<const float4*>(src + lcol * 4);
    *reinterpret_cast<float4*>(keys_out + ((size_t)nh * SP1 + s) * E_ + lcol * 4) = k4;

    float p = q4.x * k4.x + q4.y * k4.y + q4.z * k4.z + q4.w * k4.w;
    p += __shfl_xor(p, 1);
    p += __shfl_xor(p, 2);
    p += __shfl_xor(p, 4);
    p += __shfl_xor(p, 8);
    p += __shfl_xor(p, 16);
    if (lcol == 0) scores[(size_t)nh * SP1 + s] = p;
  }
}

// ---------------------------------------------------------------------------
// k2_mix: talking-heads 16x16 mix over the head axis.
//   out[n,g,s] = sum_h w[g,h] * in[n,h,s].  One thread per (n,s) column.
// ---------------------------------------------------------------------------
__global__ __launch_bounds__(256) void k2_mix(
    const float* __restrict__ w, const float* __restrict__ in,
    float* __restrict__ out)
{
  __shared__ float wl[H_ * H_];
  const int tid = threadIdx.x;
  if (tid < H_ * H_) wl[tid] = w[tid];
  __syncthreads();

  const int g = blockIdx.x * 256 + tid;  // over N_*SP1 columns
  const int n = g / SP1;
  const int s = g % SP1;

  float v[H_];
  #pragma unroll
  for (int h = 0; h < H_; ++h)
    v[h] = in[((size_t)(n * H_ + h)) * SP1 + s];

  #pragma unroll
  for (int gh = 0; gh < H_; ++gh) {
    float acc = 0.0f;
    #pragma unroll
    for (int h = 0; h < H_; ++h) acc += wl[gh * H_ + h] * v[h];
    out[((size_t)(n * H_ + gh)) * SP1 + s] = acc;
  }
}

// ---------------------------------------------------------------------------
// k2_softmax: in-place tempered softmax over s for one (n,g) row per block.
// ---------------------------------------------------------------------------
__global__ __launch_bounds__(256) void k2_softmax(float* __restrict__ a)
{
  __shared__ float vals[SP1];
  __shared__ float red[8];
  const int row = blockIdx.x;  // NH rows
  const int tid = threadIdx.x;
  const int wave = tid >> 6;
  const int lane = tid & 63;
  const float temp = 0.08838834764831845f;  // 1/sqrt(128)

  float* rp = a + (size_t)row * SP1;

  float lmax = -3.4e38f;
  #pragma unroll
  for (int k = 0; k < SP1 / 256; ++k) {
    float x = rp[tid + k * 256] * temp;
    vals[tid + k * 256] = x;
    lmax = fmaxf(lmax, x);
  }
  #pragma unroll
  for (int m = 1; m <= 32; m <<= 1) lmax = fmaxf(lmax, __shfl_xor(lmax, m));
  if (lane == 0) red[wave] = lmax;
  __syncthreads();
  const float bmax = fmaxf(fmaxf(red[0], red[1]), fmaxf(red[2], red[3]));

  float lsum = 0.0f;
  #pragma unroll
  for (int k = 0; k < SP1 / 256; ++k) {
    float e = __expf(vals[tid + k * 256] - bmax);
    vals[tid + k * 256] = e;
    lsum += e;
  }
  #pragma unroll
  for (int m = 1; m <= 32; m <<= 1) lsum += __shfl_xor(lsum, m);
  if (lane == 0) red[4 + wave] = lsum;  // disjoint slots: no WAR with red[0..3]
  __syncthreads();
  const float inv = 1.0f / (red[4] + red[5] + red[6] + red[7]);

  #pragma unroll
  for (int k = 0; k < SP1 / 256; ++k)
    rp[tid + k * 256] = vals[tid + k * 256] * inv;
}

// ---------------------------------------------------------------------------
// k3: stream values_cache + appended value -> values_out, and accumulate
//     partial[d] = sum_s A2[n,h,s] * v[n,h,s,d] per block chunk (registers),
//     reduced through LDS to a per-block partial (deterministic, no atomics).
// ---------------------------------------------------------------------------
__global__ __launch_bounds__(256) void k3_values(
    const float* __restrict__ value, const float* __restrict__ values_cache,
    const float* __restrict__ a2, float* __restrict__ values_out,
    float* __restrict__ partials)
{
  __shared__ float lds[8][128];
  const int bid   = blockIdx.x;
  const int nh    = bid / CHUNKS;
  const int chunk = bid % CHUNKS;
  const int tid   = threadIdx.x;
  const int wave  = tid >> 6;
  const int lane  = tid & 63;
  const int half  = lane >> 5;
  const int lcol  = lane & 31;
  const int group = wave * 2 + half;

  float4 acc = {0.0f, 0.0f, 0.0f, 0.0f};

  #pragma unroll 4
  for (int it = 0; it < ROWS_PER_BLOCK / 8; ++it) {
    const int r = it * 8 + wave * 2 + half;
    const int s = chunk * ROWS_PER_BLOCK + r;
    const float* src = (s < S_) ? (values_cache + ((size_t)nh * S_ + s) * D_)
                                : (value + (size_t)nh * D_);
    float4 v4 = *reinterpret_cast<const float4*>(src + lcol * 4);
    *reinterpret_cast<float4*>(values_out + ((size_t)nh * SP1 + s) * D_ + lcol * 4) = v4;

    const float w = a2[(size_t)nh * SP1 + s];
    acc.x += w * v4.x;
    acc.y += w * v4.y;
    acc.z += w * v4.z;
    acc.w += w * v4.w;
  }

  *reinterpret_cast<float4*>(&lds[group][lcol * 4]) = acc;
  __syncthreads();
  if (tid < 128) {
    float sum = 0.0f;
    #pragma unroll
    for (int gq = 0; gq < 8; ++gq) sum += lds[gq][tid];
    partials[(size_t)bid * 128 + tid] = sum;
  }
}

// ---------------------------------------------------------------------------
// k4: reduce per-chunk partials into V output. One thread per (n,h,d).
// ---------------------------------------------------------------------------
__global__ __launch_bounds__(256) void k4_reduce(
    const float* __restrict__ partials, float* __restrict__ v_out)
{
  const int g = blockIdx.x * 256 + threadIdx.x;  // NH*128
  const int nh = g >> 7;
  const int d = g & 127;
  float s = 0.0f;
  #pragma unroll
  for (int c = 0; c < CHUNKS; ++c)
    s += partials[((size_t)(nh * CHUNKS + c)) * 128 + d];
  v_out[g] = s;
}

extern "C" void kernel_launch(void* const* d_in, const int* in_sizes, int n_in,
                              void* d_out, int out_size, void* d_ws, size_t ws_size,
                              hipStream_t stream) {
  const float* query        = (const float*)d_in[0];
  const float* key          = (const float*)d_in[1];
  const float* value        = (const float*)d_in[2];
  const float* keys_cache   = (const float*)d_in[3];
  const float* values_cache = (const float*)d_in[4];
  const float* w_pre        = (const float*)d_in[5];
  const float* w_post       = (const float*)d_in[6];

  float* out = (float*)d_out;
  float* v_out      = out;                                  // [N,H,D]
  float* keys_out   = out + (size_t)NH * D_;                // [N,H,SP1,E]
  float* values_out = keys_out + (size_t)NH * SP1 * E_;     // [N,H,SP1,D]

  float* buf0     = (float*)d_ws;          // scores, later A2   [NH,SP1]
  float* buf1     = buf0 + (size_t)NH * SP1;  // QKmix -> A in place
  float* partials = buf1 + (size_t)NH * SP1;  // [NH*CHUNKS, 128]

  // 1. keys copy + QK scores
  k1_keys_scores<<<NH * CHUNKS, 256, 0, stream>>>(query, key, keys_cache,
                                                  keys_out, buf0);
  // 2. pre-softmax talking heads
  k2_mix<<<(N_ * SP1) / 256, 256, 0, stream>>>(w_pre, buf0, buf1);
  // 3. tempered softmax per (n,g) row
  k2_softmax<<<NH, 256, 0, stream>>>(buf1);
  // 4. post-softmax talking heads
  k2_mix<<<(N_ * SP1) / 256, 256, 0, stream>>>(w_post, buf1, buf0);
  // 5. values copy + fused weighted readout partials
  k3_values<<<NH * CHUNKS, 256, 0, stream>>>(value, values_cache, buf0,
                                             values_out, partials);
  // 6. final reduce -> V
  k4_reduce<<<(NH * 128) / 256, 256, 0, stream>>>(partials, v_out);
}

// Round 4
// 442.157 us; speedup vs baseline: 1.0179x; 1.0179x over previous
//
#include <hip/hip_runtime.h>
#include <cstddef>

// Problem constants (from reference setup_inputs).
constexpr int N_  = 32;
constexpr int H_  = 16;
constexpr int E_  = 128;   // = D
constexpr int D_  = 128;
constexpr int S_  = 2047;
constexpr int SP1 = 2048;  // S+1
constexpr int NH  = N_ * H_;

constexpr int ROWS_PER_BLOCK = 256;
constexpr int CHUNKS = SP1 / ROWS_PER_BLOCK;  // 8

// Native clang vector type: accepted by __builtin_nontemporal_load/store
// (HIP_vector_type float4 is a struct and is rejected).
typedef float vfloat4 __attribute__((ext_vector_type(4)));

// ---------------------------------------------------------------------------
// k1: stream keys_cache + appended key -> keys_out (nontemporal), and compute
//     scores[n,h,s] = dot(query[n,h,:], keys[n,h,s,:]) in the same pass.
// 256 thr = 4 waves; each 32-lane half-wave handles one row (128 floats) per
// iteration via float4; 32-lane shuffle reduce for the dot product.
// ---------------------------------------------------------------------------
__global__ __launch_bounds__(256) void k1_keys_scores(
    const float* __restrict__ query, const float* __restrict__ key,
    const float* __restrict__ keys_cache,
    float* __restrict__ keys_out, float* __restrict__ scores)
{
  const int bid   = blockIdx.x;
  const int nh    = bid / CHUNKS;
  const int chunk = bid % CHUNKS;
  const int tid   = threadIdx.x;
  const int wave  = tid >> 6;
  const int lane  = tid & 63;
  const int half  = lane >> 5;
  const int lcol  = lane & 31;

  const vfloat4 q4 = *reinterpret_cast<const vfloat4*>(query + (size_t)nh * E_ + lcol * 4);

  #pragma unroll 8
  for (int it = 0; it < ROWS_PER_BLOCK / 8; ++it) {
    const int r = it * 8 + wave * 2 + half;
    const int s = chunk * ROWS_PER_BLOCK + r;
    const float* src = (s < S_) ? (keys_cache + ((size_t)nh * S_ + s) * E_)
                                : (key + (size_t)nh * E_);
    vfloat4 k4 = __builtin_nontemporal_load(
        reinterpret_cast<const vfloat4*>(src + lcol * 4));
    __builtin_nontemporal_store(k4,
        reinterpret_cast<vfloat4*>(keys_out + ((size_t)nh * SP1 + s) * E_ + lcol * 4));

    float p = q4.x * k4.x + q4.y * k4.y + q4.z * k4.z + q4.w * k4.w;
    p += __shfl_xor(p, 1);
    p += __shfl_xor(p, 2);
    p += __shfl_xor(p, 4);
    p += __shfl_xor(p, 8);
    p += __shfl_xor(p, 16);
    if (lcol == 0) scores[(size_t)nh * SP1 + s] = p;
  }
}

// ---------------------------------------------------------------------------
// k2: fused pre-softmax talking-heads mix + tempered softmax.
// One block per (n,g) row: mixed[s] = temp * sum_h w_pre[g,h]*scores[n,h,s],
// built on the fly (scores[n,:,:] is only 128KB -> L2-resident across the
// 16 g-blocks of each n), then softmax over s entirely in registers.
// ---------------------------------------------------------------------------
__global__ __launch_bounds__(256) void k2_mix_softmax(
    const float* __restrict__ w_pre, const float* __restrict__ scores,
    float* __restrict__ a_out)
{
  __shared__ float wl[H_];
  __shared__ float red[8];
  const int n = blockIdx.x >> 4;
  const int g = blockIdx.x & 15;
  const int tid = threadIdx.x;
  const int wave = tid >> 6;
  const int lane = tid & 63;
  const float temp = 0.08838834764831845f;  // 1/sqrt(128)

  if (tid < H_) wl[tid] = w_pre[g * H_ + tid];
  __syncthreads();

  const float* base = scores + (size_t)n * H_ * SP1;
  float x[SP1 / 256];
  float lmax = -3.4e38f;
  #pragma unroll
  for (int k = 0; k < SP1 / 256; ++k) {
    const int s = tid + k * 256;
    float acc = 0.0f;
    #pragma unroll
    for (int h = 0; h < H_; ++h) acc += wl[h] * base[(size_t)h * SP1 + s];
    acc *= temp;
    x[k] = acc;
    lmax = fmaxf(lmax, acc);
  }
  #pragma unroll
  for (int m = 1; m <= 32; m <<= 1) lmax = fmaxf(lmax, __shfl_xor(lmax, m));
  if (lane == 0) red[wave] = lmax;
  __syncthreads();
  const float bmax = fmaxf(fmaxf(red[0], red[1]), fmaxf(red[2], red[3]));

  float lsum = 0.0f;
  #pragma unroll
  for (int k = 0; k < SP1 / 256; ++k) {
    float e = __expf(x[k] - bmax);
    x[k] = e;
    lsum += e;
  }
  #pragma unroll
  for (int m = 1; m <= 32; m <<= 1) lsum += __shfl_xor(lsum, m);
  if (lane == 0) red[4 + wave] = lsum;
  __syncthreads();
  const float inv = 1.0f / (red[4] + red[5] + red[6] + red[7]);

  float* out = a_out + (size_t)(n * H_ + g) * SP1;
  #pragma unroll
  for (int k = 0; k < SP1 / 256; ++k)
    out[tid + k * 256] = x[k] * inv;
}

// ---------------------------------------------------------------------------
// k3: per (nh=n*16+g, chunk) block:
//   Prologue: compute the 256 post-mixed weights for this chunk into LDS:
//     A2[n,g,s] = sum_h w_post[g,h] * A[n,h,s]   (A is L2-resident, 8.4MB)
//   Main: stream values_cache + appended value -> values_out (nontemporal),
//   accumulate partial[d] = sum_s A2[s] * v[n,g,s,d] in registers, reduce
//   through LDS to a per-block partial (deterministic, no atomics).
// NOTE: post-mix must NOT be folded past the readout — values are per-head,
// so V[n,g,d] = sum_s A2[n,g,s]*values[n,g,s,d] (head g values!).
// ---------------------------------------------------------------------------
__global__ __launch_bounds__(256) void k3_values(
    const float* __restrict__ value, const float* __restrict__ values_cache,
    const float* __restrict__ a, const float* __restrict__ w_post,
    float* __restrict__ values_out, float* __restrict__ partials)
{
  __shared__ float lds[8][128];
  __shared__ float a2[ROWS_PER_BLOCK];
  const int bid   = blockIdx.x;
  const int nh    = bid / CHUNKS;
  const int chunk = bid % CHUNKS;
  const int tid   = threadIdx.x;
  const int wave  = tid >> 6;
  const int lane  = tid & 63;
  const int half  = lane >> 5;
  const int lcol  = lane & 31;
  const int group = wave * 2 + half;

  // Prologue: 256 mixed weights (one per thread).
  {
    const int n = nh >> 4;
    const int g = nh & 15;
    const int s = chunk * ROWS_PER_BLOCK + tid;
    const float* abase = a + (size_t)n * H_ * SP1 + s;
    const float* wrow  = w_post + g * H_;
    float acc = 0.0f;
    #pragma unroll
    for (int h = 0; h < H_; ++h) acc += wrow[h] * abase[(size_t)h * SP1];
    a2[tid] = acc;
  }
  __syncthreads();

  float accx = 0.0f, accy = 0.0f, accz = 0.0f, accw = 0.0f;

  #pragma unroll 8
  for (int it = 0; it < ROWS_PER_BLOCK / 8; ++it) {
    const int r = it * 8 + wave * 2 + half;
    const int s = chunk * ROWS_PER_BLOCK + r;
    const float* src = (s < S_) ? (values_cache + ((size_t)nh * S_ + s) * D_)
                                : (value + (size_t)nh * D_);
    vfloat4 v4 = __builtin_nontemporal_load(
        reinterpret_cast<const vfloat4*>(src + lcol * 4));
    __builtin_nontemporal_store(v4,
        reinterpret_cast<vfloat4*>(values_out + ((size_t)nh * SP1 + s) * D_ + lcol * 4));

    const float w = a2[r];  // broadcast within half-wave: conflict-free
    accx += w * v4.x;
    accy += w * v4.y;
    accz += w * v4.z;
    accw += w * v4.w;
  }

  lds[group][lcol * 4 + 0] = accx;
  lds[group][lcol * 4 + 1] = accy;
  lds[group][lcol * 4 + 2] = accz;
  lds[group][lcol * 4 + 3] = accw;
  __syncthreads();
  if (tid < 128) {
    float sum = 0.0f;
    #pragma unroll
    for (int gq = 0; gq < 8; ++gq) sum += lds[gq][tid];
    partials[(size_t)bid * 128 + tid] = sum;
  }
}

// ---------------------------------------------------------------------------
// k4: reduce per-chunk partials into V output. One thread per (n,h,d).
// ---------------------------------------------------------------------------
__global__ __launch_bounds__(256) void k4_reduce(
    const float* __restrict__ partials, float* __restrict__ v_out)
{
  const int g = blockIdx.x * 256 + threadIdx.x;  // NH*128
  const int nh = g >> 7;
  const int d = g & 127;
  float s = 0.0f;
  #pragma unroll
  for (int c = 0; c < CHUNKS; ++c)
    s += partials[((size_t)(nh * CHUNKS + c)) * 128 + d];
  v_out[g] = s;
}

extern "C" void kernel_launch(void* const* d_in, const int* in_sizes, int n_in,
                              void* d_out, int out_size, void* d_ws, size_t ws_size,
                              hipStream_t stream) {
  const float* query        = (const float*)d_in[0];
  const float* key          = (const float*)d_in[1];
  const float* value        = (const float*)d_in[2];
  const float* keys_cache   = (const float*)d_in[3];
  const float* values_cache = (const float*)d_in[4];
  const float* w_pre        = (const float*)d_in[5];
  const float* w_post       = (const float*)d_in[6];

  float* out = (float*)d_out;
  float* v_out      = out;                                  // [N,H,D]
  float* keys_out   = out + (size_t)NH * D_;                // [N,H,SP1,E]
  float* values_out = keys_out + (size_t)NH * SP1 * E_;     // [N,H,SP1,D]

  float* buf0     = (float*)d_ws;             // raw scores      [NH,SP1]
  float* buf1     = buf0 + (size_t)NH * SP1;  // A (softmaxed)   [NH,SP1]
  float* partials = buf1 + (size_t)NH * SP1;  // [NH*CHUNKS, 128]

  // 1. keys copy + QK scores
  k1_keys_scores<<<NH * CHUNKS, 256, 0, stream>>>(query, key, keys_cache,
                                                  keys_out, buf0);
  // 2. fused pre-mix + softmax -> A
  k2_mix_softmax<<<NH, 256, 0, stream>>>(w_pre, buf0, buf1);
  // 3. post-mix (fused prologue) + values copy + weighted readout partials
  k3_values<<<NH * CHUNKS, 256, 0, stream>>>(value, values_cache, buf1, w_post,
                                             values_out, partials);
  // 4. chunk-reduce -> V
  k4_reduce<<<(NH * 128) / 256, 256, 0, stream>>>(partials, v_out);
}

// Round 5
// 436.892 us; speedup vs baseline: 1.0301x; 1.0121x over previous
//
#include <hip/hip_runtime.h>
#include <cstddef>

// Problem constants (from reference setup_inputs).
constexpr int N_  = 32;
constexpr int H_  = 16;
constexpr int E_  = 128;   // = D
constexpr int D_  = 128;
constexpr int S_  = 2047;
constexpr int SP1 = 2048;  // S+1
constexpr int NH  = N_ * H_;

constexpr int ROWS_PER_BLOCK = 256;
constexpr int CHUNKS = SP1 / ROWS_PER_BLOCK;  // 8

// Native clang vector type: accepted by __builtin_nontemporal_load/store
// (HIP_vector_type float4 is a struct and is rejected).
typedef float vfloat4 __attribute__((ext_vector_type(4)));

// ---------------------------------------------------------------------------
// k1: stream keys_cache + appended key -> keys_out (cached loads, nt stores),
// and compute scores[n,h,s] = dot(query[n,h,:], keys[n,h,s,:]) in-pass.
// Scores staged in LDS, written coalesced at block end (plain stores: k2
// re-reads them soon, keep them L2-resident).
// ---------------------------------------------------------------------------
__global__ __launch_bounds__(256) void k1_keys_scores(
    const float* __restrict__ query, const float* __restrict__ key,
    const float* __restrict__ keys_cache,
    float* __restrict__ keys_out, float* __restrict__ scores)
{
  __shared__ float sc[ROWS_PER_BLOCK];
  const int bid   = blockIdx.x;
  const int nh    = bid / CHUNKS;
  const int chunk = bid % CHUNKS;
  const int tid   = threadIdx.x;
  const int wave  = tid >> 6;
  const int lane  = tid & 63;
  const int half  = lane >> 5;
  const int lcol  = lane & 31;

  const vfloat4 q4 = *reinterpret_cast<const vfloat4*>(query + (size_t)nh * E_ + lcol * 4);

  #pragma unroll 8
  for (int it = 0; it < ROWS_PER_BLOCK / 8; ++it) {
    const int r = it * 8 + wave * 2 + half;
    const int s = chunk * ROWS_PER_BLOCK + r;
    const float* src = (s < S_) ? (keys_cache + ((size_t)nh * S_ + s) * E_)
                                : (key + (size_t)nh * E_);
    vfloat4 k4 = *reinterpret_cast<const vfloat4*>(src + lcol * 4);
    __builtin_nontemporal_store(k4,
        reinterpret_cast<vfloat4*>(keys_out + ((size_t)nh * SP1 + s) * E_ + lcol * 4));

    float p = q4.x * k4.x + q4.y * k4.y + q4.z * k4.z + q4.w * k4.w;
    p += __shfl_xor(p, 1);
    p += __shfl_xor(p, 2);
    p += __shfl_xor(p, 4);
    p += __shfl_xor(p, 8);
    p += __shfl_xor(p, 16);
    if (lcol == 0) sc[r] = p;
  }
  __syncthreads();
  // One coalesced 1KB store per block.
  scores[(size_t)nh * SP1 + chunk * ROWS_PER_BLOCK + tid] = sc[tid];
}

// ---------------------------------------------------------------------------
// k2: fused pre-softmax talking-heads mix + tempered softmax.
// One block (512 thr) per (n,g) row; each thread owns 4 consecutive s
// (one float4 per head row -> coalesced 16B loads, 32 loads/thread).
// scores[n,:,:] is 128KB -> L2-resident across the 16 g-blocks per n.
// ---------------------------------------------------------------------------
__global__ __launch_bounds__(512) void k2_mix_softmax(
    const float* __restrict__ w_pre, const float* __restrict__ scores,
    float* __restrict__ a_out)
{
  __shared__ float wl[H_];
  __shared__ float redmax[8];
  __shared__ float redsum[8];
  const int n = blockIdx.x >> 4;
  const int g = blockIdx.x & 15;
  const int tid = threadIdx.x;
  const int wave = tid >> 6;
  const int lane = tid & 63;
  const float temp = 0.08838834764831845f;  // 1/sqrt(128)

  if (tid < H_) wl[tid] = w_pre[g * H_ + tid];
  __syncthreads();

  const float* base = scores + (size_t)n * H_ * SP1 + tid * 4;
  float a0 = 0.0f, a1 = 0.0f, a2 = 0.0f, a3 = 0.0f;
  #pragma unroll
  for (int h = 0; h < H_; ++h) {
    vfloat4 v = *reinterpret_cast<const vfloat4*>(base + (size_t)h * SP1);
    const float w = wl[h];
    a0 += w * v.x; a1 += w * v.y; a2 += w * v.z; a3 += w * v.w;
  }
  a0 *= temp; a1 *= temp; a2 *= temp; a3 *= temp;

  float lmax = fmaxf(fmaxf(a0, a1), fmaxf(a2, a3));
  #pragma unroll
  for (int m = 1; m <= 32; m <<= 1) lmax = fmaxf(lmax, __shfl_xor(lmax, m));
  if (lane == 0) redmax[wave] = lmax;
  __syncthreads();
  float bmax = redmax[0];
  #pragma unroll
  for (int w = 1; w < 8; ++w) bmax = fmaxf(bmax, redmax[w]);

  a0 = __expf(a0 - bmax); a1 = __expf(a1 - bmax);
  a2 = __expf(a2 - bmax); a3 = __expf(a3 - bmax);
  float lsum = a0 + a1 + a2 + a3;
  #pragma unroll
  for (int m = 1; m <= 32; m <<= 1) lsum += __shfl_xor(lsum, m);
  if (lane == 0) redsum[wave] = lsum;
  __syncthreads();
  float tot = 0.0f;
  #pragma unroll
  for (int w = 0; w < 8; ++w) tot += redsum[w];
  const float inv = 1.0f / tot;

  vfloat4 o = {a0 * inv, a1 * inv, a2 * inv, a3 * inv};
  *reinterpret_cast<vfloat4*>(a_out + (size_t)(n * H_ + g) * SP1 + tid * 4) = o;
}

// ---------------------------------------------------------------------------
// k3: per (nh=n*16+g, chunk) block:
//   Prologue: A2[n,g,s] = sum_h w_post[g,h] * A[n,h,s] into LDS (A is
//   L2-resident). Main: stream values_cache + appended value -> values_out
//   (cached loads, nt stores), accumulate partial[d] = sum_s A2[s]*v[s,d]
//   in registers, reduce through LDS to per-block partials (deterministic).
// NOTE: post-mix must NOT be folded past the readout — values are per-head:
// V[n,g,d] = sum_s A2[n,g,s]*values[n,g,s,d] (head g values!).
// ---------------------------------------------------------------------------
__global__ __launch_bounds__(256) void k3_values(
    const float* __restrict__ value, const float* __restrict__ values_cache,
    const float* __restrict__ a, const float* __restrict__ w_post,
    float* __restrict__ values_out, float* __restrict__ partials)
{
  __shared__ float lds[8][128];
  __shared__ float a2[ROWS_PER_BLOCK];
  const int bid   = blockIdx.x;
  const int nh    = bid / CHUNKS;
  const int chunk = bid % CHUNKS;
  const int tid   = threadIdx.x;
  const int wave  = tid >> 6;
  const int lane  = tid & 63;
  const int half  = lane >> 5;
  const int lcol  = lane & 31;
  const int group = wave * 2 + half;

  // Prologue: 256 mixed weights (one per thread).
  {
    const int n = nh >> 4;
    const int g = nh & 15;
    const int s = chunk * ROWS_PER_BLOCK + tid;
    const float* abase = a + (size_t)n * H_ * SP1 + s;
    const float* wrow  = w_post + g * H_;
    float acc = 0.0f;
    #pragma unroll
    for (int h = 0; h < H_; ++h) acc += wrow[h] * abase[(size_t)h * SP1];
    a2[tid] = acc;
  }
  __syncthreads();

  float accx = 0.0f, accy = 0.0f, accz = 0.0f, accw = 0.0f;

  #pragma unroll 8
  for (int it = 0; it < ROWS_PER_BLOCK / 8; ++it) {
    const int r = it * 8 + wave * 2 + half;
    const int s = chunk * ROWS_PER_BLOCK + r;
    const float* src = (s < S_) ? (values_cache + ((size_t)nh * S_ + s) * D_)
                                : (value + (size_t)nh * D_);
    vfloat4 v4 = *reinterpret_cast<const vfloat4*>(src + lcol * 4);
    __builtin_nontemporal_store(v4,
        reinterpret_cast<vfloat4*>(values_out + ((size_t)nh * SP1 + s) * D_ + lcol * 4));

    const float w = a2[r];  // broadcast within half-wave: conflict-free
    accx += w * v4.x;
    accy += w * v4.y;
    accz += w * v4.z;
    accw += w * v4.w;
  }

  lds[group][lcol * 4 + 0] = accx;
  lds[group][lcol * 4 + 1] = accy;
  lds[group][lcol * 4 + 2] = accz;
  lds[group][lcol * 4 + 3] = accw;
  __syncthreads();
  if (tid < 128) {
    float sum = 0.0f;
    #pragma unroll
    for (int gq = 0; gq < 8; ++gq) sum += lds[gq][tid];
    partials[(size_t)bid * 128 + tid] = sum;
  }
}

// ---------------------------------------------------------------------------
// k4: reduce per-chunk partials into V output. One thread per (n,h,d).
// ---------------------------------------------------------------------------
__global__ __launch_bounds__(256) void k4_reduce(
    const float* __restrict__ partials, float* __restrict__ v_out)
{
  const int g = blockIdx.x * 256 + threadIdx.x;  // NH*128
  const int nh = g >> 7;
  const int d = g & 127;
  float s = 0.0f;
  #pragma unroll
  for (int c = 0; c < CHUNKS; ++c)
    s += partials[((size_t)(nh * CHUNKS + c)) * 128 + d];
  v_out[g] = s;
}

extern "C" void kernel_launch(void* const* d_in, const int* in_sizes, int n_in,
                              void* d_out, int out_size, void* d_ws, size_t ws_size,
                              hipStream_t stream) {
  const float* query        = (const float*)d_in[0];
  const float* key          = (const float*)d_in[1];
  const float* value        = (const float*)d_in[2];
  const float* keys_cache   = (const float*)d_in[3];
  const float* values_cache = (const float*)d_in[4];
  const float* w_pre        = (const float*)d_in[5];
  const float* w_post       = (const float*)d_in[6];

  float* out = (float*)d_out;
  float* v_out      = out;                                  // [N,H,D]
  float* keys_out   = out + (size_t)NH * D_;                // [N,H,SP1,E]
  float* values_out = keys_out + (size_t)NH * SP1 * E_;     // [N,H,SP1,D]

  float* buf0     = (float*)d_ws;             // raw scores      [NH,SP1]
  float* buf1     = buf0 + (size_t)NH * SP1;  // A (softmaxed)   [NH,SP1]
  float* partials = buf1 + (size_t)NH * SP1;  // [NH*CHUNKS, 128]

  // 1. keys copy + QK scores
  k1_keys_scores<<<NH * CHUNKS, 256, 0, stream>>>(query, key, keys_cache,
                                                  keys_out, buf0);
  // 2. fused pre-mix + softmax -> A
  k2_mix_softmax<<<NH, 512, 0, stream>>>(w_pre, buf0, buf1);
  // 3. post-mix (fused prologue) + values copy + weighted readout partials
  k3_values<<<NH * CHUNKS, 256, 0, stream>>>(value, values_cache, buf1, w_post,
                                             values_out, partials);
  // 4. chunk-reduce -> V
  k4_reduce<<<(NH * 128) / 256, 256, 0, stream>>>(partials, v_out);
}